// Round 3
// baseline (16050.899 us; speedup 1.0000x reference)
//
#include <hip/hip_runtime.h>
#include <stdint.h>

typedef unsigned int u32;
typedef unsigned long long u64;

#define SCOPE_AGENT __HIP_MEMORY_SCOPE_AGENT

#define H 256
#define L_ATT 512
#define G3 768
#define EOS_TOK 1

// role layout: 1 control + 32 A + 16 B + 32 G + 175 V = 256 blocks
#define NB_A 32
#define NB_B 16
#define NB_G 32
#define BID_A0 1
#define BID_B0 (BID_A0 + NB_A)   /* 33 */
#define BID_G0 (BID_B0 + NB_B)   /* 49 */
#define BID_V0 (BID_G0 + NB_G)   /* 81 */
#define NBLK 256
#define NV (NBLK - BID_V0)       /* 175 */

#define STOPBIT 0x80000000ull
#define SPIN_LIMIT 200000000ull   /* ~2e8 realtime ticks (~2s @100MHz): finite bail-out */

// ---------------- atomics / spin helpers ----------------
__device__ __forceinline__ u32 ld_rlx(u32* p){ return __hip_atomic_load(p, __ATOMIC_RELAXED, SCOPE_AGENT); }
__device__ __forceinline__ u32 ld_acq(u32* p){ return __hip_atomic_load(p, __ATOMIC_ACQUIRE, SCOPE_AGENT); }
__device__ __forceinline__ u64 ld64_rlx(u64* p){ return __hip_atomic_load(p, __ATOMIC_RELAXED, SCOPE_AGENT); }
__device__ __forceinline__ u64 ld64_acq(u64* p){ return __hip_atomic_load(p, __ATOMIC_ACQUIRE, SCOPE_AGENT); }
__device__ __forceinline__ void st64_rel(u64* p, u64 v){ __hip_atomic_store(p, v, __ATOMIC_RELEASE, SCOPE_AGENT); }
__device__ __forceinline__ float ldf_rlx(float* p){ return __hip_atomic_load(p, __ATOMIC_RELAXED, SCOPE_AGENT); }

// spin until *ctr >= target. Returns 0 ok, 1 stop-flag seen, 2 timeout.
__device__ __forceinline__ int spin_ctr(u32* ctr, u32 target, u64* flagp) {
  u64 t0 = __builtin_amdgcn_s_memrealtime();
  u32 k = 0;
  for (;;) {
    if (ld_rlx(ctr) >= target) { (void)ld_acq(ctr); return 0; }
    ++k;
    if (flagp && ((k & 15u) == 0u)) {
      u64 f = ld64_rlx(flagp);
      if (f & STOPBIT) { (void)ld64_acq(flagp); return 1; }
    }
    if ((k & 255u) == 0u) {
      if (__builtin_amdgcn_s_memrealtime() - t0 > SPIN_LIMIT) return 2;
    }
    __builtin_amdgcn_s_sleep(2);
  }
}
// spin until flag step >= step (or stop/timeout); returns flag value (timeout -> STOPBIT)
__device__ __forceinline__ u64 spin_flag(u64* flagp, u32 step) {
  u64 t0 = __builtin_amdgcn_s_memrealtime();
  u32 k = 0;
  for (;;) {
    u64 f = ld64_rlx(flagp);
    if ((u32)(f >> 32) >= step || (f & STOPBIT)) { (void)ld64_acq(flagp); return f; }
    ++k;
    if ((k & 255u) == 0u) {
      if (__builtin_amdgcn_s_memrealtime() - t0 > SPIN_LIMIT) return STOPBIT;
    }
    __builtin_amdgcn_s_sleep(2);
  }
}

// ---------------- math helpers ----------------
__device__ __forceinline__ float sigf(float x){ return 1.f/(1.f + expf(-x)); }
__device__ __forceinline__ float dot4(float4 a, float4 b, float acc){
  acc = fmaf(a.x,b.x,acc); acc = fmaf(a.y,b.y,acc); acc = fmaf(a.z,b.z,acc); return fmaf(a.w,b.w,acc);
}
__device__ __forceinline__ u32 f2ord(float x){
  u32 b = __float_as_uint(x); return (b & 0x80000000u) ? ~b : (b | 0x80000000u);
}
__device__ __forceinline__ float rsum64(float v){
  v += __shfl_xor(v,1); v += __shfl_xor(v,2); v += __shfl_xor(v,4);
  v += __shfl_xor(v,8); v += __shfl_xor(v,16); v += __shfl_xor(v,32); return v;
}
__device__ __forceinline__ float rsum32(float v){
  v += __shfl_xor(v,1); v += __shfl_xor(v,2); v += __shfl_xor(v,4);
  v += __shfl_xor(v,8); v += __shfl_xor(v,16); return v;
}
__device__ __forceinline__ float rsum16(float v){
  v += __shfl_xor(v,1); v += __shfl_xor(v,2); v += __shfl_xor(v,4); v += __shfl_xor(v,8); return v;
}
__device__ __forceinline__ float rmaxf64(float v){
  v = fmaxf(v,__shfl_xor(v,1)); v = fmaxf(v,__shfl_xor(v,2)); v = fmaxf(v,__shfl_xor(v,4));
  v = fmaxf(v,__shfl_xor(v,8)); v = fmaxf(v,__shfl_xor(v,16)); v = fmaxf(v,__shfl_xor(v,32)); return v;
}
__device__ __forceinline__ double rsumd64(double v){
  v += __shfl_xor(v,1); v += __shfl_xor(v,2); v += __shfl_xor(v,4);
  v += __shfl_xor(v,8); v += __shfl_xor(v,16); v += __shfl_xor(v,32); return v;
}
__device__ __forceinline__ u64 rmaxk64(u64 k){
  u64 o;
  o=__shfl_xor(k,1);  k=k>o?k:o; o=__shfl_xor(k,2);  k=k>o?k:o;
  o=__shfl_xor(k,4);  k=k>o?k:o; o=__shfl_xor(k,8);  k=k>o?k:o;
  o=__shfl_xor(k,16); k=k>o?k:o; o=__shfl_xor(k,32); k=k>o?k:o;
  return k;
}

// ---------------- K0: init workspace head + encout ----------------
__global__ __launch_bounds__(256) void k_init(u32* head, int nhead, float* encout, int nenc) {
  int i = blockIdx.x*blockDim.x + threadIdx.x;
  int st = gridDim.x*blockDim.x;
  for (int k = i; k < nhead; k += st) head[k] = 0u;
  for (int k = i; k < nenc; k += st) encout[k] = 0.f;
}

// sentinel: ws too small
__global__ __launch_bounds__(64) void k_sentinel(float* out, float v) {
  if (threadIdx.x == 0) out[0] = v;
}

// ---------------- K1: encoder gi GEMM (all steps parallel) ----------------
__global__ __launch_bounds__(512) void k_gi(const int* __restrict__ in_tok, const int* __restrict__ p_ilen,
                                            const float* __restrict__ emb, const float* __restrict__ Wih,
                                            const float* __restrict__ bih, float* __restrict__ gi_buf) {
  int t = blockIdx.x;
  if (t >= p_ilen[0]) return;
  __shared__ float se[H];
  int tid = threadIdx.x;
  if (tid < 64) ((float4*)se)[tid] = ((const float4*)(emb + (size_t)in_tok[t]*H))[tid];
  __syncthreads();
  int w = tid >> 6, l = tid & 63;
  float4 hv = ((const float4*)se)[l];
  for (int rr = 0; rr < 96; ++rr) {
    int row = rr*8 + w;
    float4 wv = ((const float4*)(Wih + (size_t)row*H))[l];
    float acc = dot4(wv, hv, 0.f);
    acc = rsum64(acc);
    if (l == 0) gi_buf[(size_t)t*G3 + row] = acc + bih[row];
  }
}

// ---------------- K2: encoder sequential scan, 16 blocks, flag-synced ----------------
__global__ __launch_bounds__(512) void k_enc(const int* __restrict__ p_ilen, const float* __restrict__ Whh,
                                             const float* __restrict__ bhh, const float* __restrict__ gi_buf,
                                             float* henc /*[2][H]*/, float* encout, u32* arrE) {
  extern __shared__ char smraw[];
  float* sW  = (float*)smraw;        // [48][256]
  float* sh  = sW + 48*H;            // 256
  float* sgh = sh + H;               // 48
  float* sbh = sgh + 48;             // 48
  int e = blockIdx.x, tid = threadIdx.x;
  int j0 = e*16;
  int ilen = p_ilen[0];
  for (int idx = tid; idx < 48*H; idx += 512) {
    int r = idx >> 8, c = idx & 255;
    int grow = (r>>4)*H + j0 + (r&15);
    sW[idx] = Whh[(size_t)grow*H + c];
  }
  if (tid < 48) { int grow = (tid>>4)*H + j0 + (tid&15); sbh[tid] = bhh[grow]; }
  __syncthreads();
  __shared__ int s_to;
  int w = tid>>6, l = tid&63;
  for (int t = 0; t < ilen; ++t) {
    if (tid == 0) s_to = spin_ctr(arrE, 16u*(u32)t, nullptr);
    __syncthreads();
    if (s_to) break;
    if (tid < 64) ((float4*)sh)[tid] = ((const float4*)(henc + (t&1)*H))[tid];
    __syncthreads();
    for (int rr = 0; rr < 6; ++rr) {
      int r = rr*8 + w;
      float4 wv = ((const float4*)(sW + r*H))[l];
      float4 hv = ((const float4*)sh)[l];
      float acc = dot4(wv, hv, 0.f);
      acc = rsum64(acc);
      if (l == 0) sgh[r] = acc + sbh[r];
    }
    __syncthreads();
    if (tid < 16) {
      int j = tid;
      const float* gi = gi_buf + (size_t)t*G3;
      float gir = gi[j0+j], giz = gi[H+j0+j], gin = gi[2*H+j0+j];
      float rg = sigf(gir + sgh[j]);
      float zg = sigf(giz + sgh[16+j]);
      float ng = tanhf(fmaf(rg, sgh[32+j], gin));
      float hold = sh[j0+j];
      float h2 = fmaf(zg, hold, (1.f-zg)*ng);
      henc[((t+1)&1)*H + j0 + j] = h2;
      encout[(size_t)t*H + j0 + j] = h2;
    }
    __syncthreads();
    if (tid == 0) { __threadfence(); atomicAdd(arrE, 1u); }
  }
}

// ---------------- K3: M = comb_W[:,256:] @ encout^T ; copy final enc h -> hdec buf0 ----------------
__global__ __launch_bounds__(512) void k_m(const int* __restrict__ p_ilen, const float* __restrict__ combW,
                                           const float* __restrict__ encout, float* __restrict__ Mm,
                                           const float* __restrict__ henc, float* __restrict__ hdec) {
  int i = blockIdx.x, tid = threadIdx.x;
  if (i == 256) {
    int ilen = p_ilen[0];
    if (tid < H) hdec[tid] = henc[(ilen&1)*H + tid];
    return;
  }
  __shared__ float sw[H];
  if (tid < 64) ((float4*)sw)[tid] = ((const float4*)(combW + (size_t)i*(2*H) + H))[tid];
  __syncthreads();
  int w = tid>>6, l = tid&63;
  float4 wv = ((const float4*)sw)[l];
  for (int lr = 0; lr < 64; ++lr) {
    int row = lr*8 + w; // 0..511
    float4 ev = ((const float4*)(encout + (size_t)row*H))[l];
    float acc = dot4(wv, ev, 0.f);
    acc = rsum64(acc);
    if (l == 0) Mm[(size_t)i*L_ATT + row] = acc;
  }
}

// ---------------- K4: persistent decoder, role-specialized, 512 thr, LDS<=52.5KB ----------------
__global__ __launch_bounds__(512, 4) void k_dec(
    const int* p_tlen, const int* target,
    const float* __restrict__ dec_emb, const float* __restrict__ attn_W,
    const float* __restrict__ attn_b, const float* __restrict__ comb_W,
    const float* __restrict__ comb_b, const float* __restrict__ Wih,
    const float* __restrict__ Whh, const float* __restrict__ bih,
    const float* __restrict__ bhh, const float* __restrict__ outW,
    const float* __restrict__ outb, const float* __restrict__ Mm,
    float* hdec, float* attnlog, float* ovec,
    double* psum, u64* pkey, float* ltgt_p,
    u64* flagT, u32* arrA, u32* arrB, u32* arrC, u32* arrC2, u32* arrV,
    float* lossout, int V, int RPB)
{
  extern __shared__ char smraw[];
  __shared__ u64 s_flag;
  __shared__ int s_stop;
  int bid = blockIdx.x, tid = threadIdx.x;
  int tlen = p_tlen[0];
  int w = tid >> 6, l = tid & 63;

  if (bid == 0) {
    // ---------------- control ----------------
    double* rd = (double*)smraw;          // [8]
    u64*    rk = (u64*)(smraw + 64);      // [8]
    double loss = 0.0;
    if (tlen <= 0) {
      if (tid == 0) { lossout[0] = 0.f; __threadfence(); st64_rel(flagT, (((u64)1)<<32) | STOPBIT); }
      return;
    }
    for (int s = 0; s < tlen; ++s) {
      if (tid == 0) s_stop = spin_ctr(arrV, (u32)NV*(u32)(s+1), nullptr);
      __syncthreads();
      if (s_stop) { // timeout: publish stop so everyone drains, flag sentinel loss
        if (tid == 0) { lossout[0] = -777.f; __threadfence(); st64_rel(flagT, (((u64)(s+1))<<32) | STOPBIT); }
        break;
      }
      double pd = 0.0; u64 pk = 0ull;
      if (tid < NV) { pd = psum[BID_V0 + tid]; pk = pkey[BID_V0 + tid]; }
      pd = rsumd64(pd); pk = rmaxk64(pk);
      if (l == 0) { rd[w] = pd; rk[w] = pk; }
      __syncthreads();
      if (tid == 0) {
        double ssum = 0.0; u64 key = 0ull;
        for (int k = 0; k < 8; ++k) { ssum += rd[k]; if (rk[k] > key) key = rk[k]; }
        int top = (int)(0xFFFFFFFFu - (u32)(key & 0xFFFFFFFFull));
        float lt = ldf_rlx(ltgt_p);
        loss += log(ssum) - (double)lt;      // -logp[tgt] = lse - logit[tgt]
        bool fin = (top == EOS_TOK) || (s == tlen - 1);
        if (fin) {
          lossout[0] = (float)loss;
          __threadfence();
          st64_rel(flagT, (((u64)(s+1))<<32) | STOPBIT);
        } else {
          st64_rel(flagT, (((u64)(s+1))<<32) | (u64)(u32)top);
        }
        s_stop = fin ? 1 : 0;
      }
      __syncthreads();
      if (s_stop) break;
      __syncthreads();
    }
  } else if (bid < BID_B0) {
    // ---------------- A blocks (32): attention logits, 16 rows each ----------------
    int a = bid - BID_A0; int r0 = a*16;
    float* sW  = (float*)smraw;          // [16][512]
    float* sh  = sW + 16*L_ATT;          // 256
    float* se  = sh + H;                 // 256
    float* sab = se + H;                 // 16
    for (int idx = tid; idx < 16*L_ATT; idx += 512) {
      int r = idx >> 9, c = idx & 511;
      sW[idx] = attn_W[(size_t)(r0 + r)*L_ATT + c];
    }
    if (tid < 16) sab[tid] = attn_b[r0 + tid];
    __syncthreads();
    int r = tid >> 5, li = tid & 31;
    for (int s = 0; s < tlen; ++s) {
      if (tid == 0) s_stop = spin_ctr(arrC, (u32)NB_G*(u32)s, flagT);
      __syncthreads();
      if (s_stop) break;
      if (tid < 64) ((float4*)sh)[tid] = ((const float4*)(hdec + (s&1)*H))[tid];
      __syncthreads();
      float ath = 0.f;
      #pragma unroll
      for (int c = 0; c < 2; ++c) {
        float4 wv = *(const float4*)(sW + r*L_ATT + H + li*4 + c*128);
        float4 hv = *(const float4*)(sh + li*4 + c*128);
        ath = dot4(wv, hv, ath);
      }
      ath = rsum32(ath);
      if (tid == 0) { u64 f = spin_flag(flagT, (u32)s); s_flag = f; s_stop = (f & STOPBIT) ? 1 : 0; }
      __syncthreads();
      if (s_stop) break;
      int tok = (int)((u32)s_flag & 0x7FFFFFFFu);
      if (tid < 64) ((float4*)se)[tid] = ((const float4*)(dec_emb + (size_t)tok*H))[tid];
      __syncthreads();
      float ate = 0.f;
      #pragma unroll
      for (int c = 0; c < 2; ++c) {
        float4 wv = *(const float4*)(sW + r*L_ATT + li*4 + c*128);
        float4 ev = *(const float4*)(se + li*4 + c*128);
        ate = dot4(wv, ev, ate);
      }
      ate = rsum32(ate);
      if (li == 0) attnlog[r0 + r] = ath + ate + sab[r];
      __syncthreads();
      if (tid == 0) { __threadfence(); atomicAdd(arrA, 1u); }
    }
  } else if (bid < BID_G0) {
    // ---------------- B blocks (16): softmax + o = relu(W1@emb + M@attn/S + b), 16 rows ----------------
    int b = bid - BID_B0; int r0 = b*16;
    float* sW1 = (float*)smraw;          // [16][256]
    float* sM  = sW1 + 16*H;             // [16][512]
    float* se  = sM + 16*L_ATT;          // 256
    float* sal = se + H;                 // 512
    float* sred= sal + L_ATT;            // 32
    float* sce = sred + 32;              // 16
    float* scb = sce + 16;               // 16
    for (int idx = tid; idx < 16*H; idx += 512) {
      int r = idx >> 8, c = idx & 255;
      sW1[idx] = comb_W[(size_t)(r0 + r)*(2*H) + c];
    }
    for (int idx = tid; idx < 16*L_ATT; idx += 512) {
      int r = idx >> 9, c = idx & 511;
      sM[idx] = Mm[(size_t)(r0 + r)*L_ATT + c];
    }
    if (tid < 16) scb[tid] = comb_b[r0 + tid];
    __syncthreads();
    int r = tid >> 5, li = tid & 31;
    for (int s = 0; s < tlen; ++s) {
      if (tid == 0) { u64 f = spin_flag(flagT, (u32)s); s_flag = f; s_stop = (f & STOPBIT) ? 1 : 0; }
      __syncthreads();
      if (s_stop) break;
      int tok = (int)((u32)s_flag & 0x7FFFFFFFu);
      if (tid < 64) ((float4*)se)[tid] = ((const float4*)(dec_emb + (size_t)tok*H))[tid];
      __syncthreads();
      float ce = 0.f;
      #pragma unroll
      for (int c = 0; c < 2; ++c) {
        float4 wv = *(const float4*)(sW1 + r*H + li*4 + c*128);
        float4 ev = *(const float4*)(se + li*4 + c*128);
        ce = dot4(wv, ev, ce);
      }
      ce = rsum32(ce);
      if (li == 0) sce[r] = ce;
      if (tid == 0) s_stop = spin_ctr(arrA, (u32)NB_A*(u32)(s+1), flagT);
      __syncthreads();
      if (s_stop) break;
      // softmax over 512 logits (one per thread)
      float x = attnlog[tid];
      sal[tid] = x;
      float wm = rmaxf64(x);
      if (l == 0) sred[w] = wm;
      __syncthreads();
      if (tid == 0) {
        float m0 = sred[0];
        for (int k = 1; k < 8; ++k) m0 = fmaxf(m0, sred[k]);
        sred[16] = m0;
      }
      __syncthreads();
      float mx = sred[16];
      float e = expf(x - mx);
      sal[tid] = e;
      float wsum = rsum64(e);
      if (l == 0) sred[w] = wsum;
      __syncthreads();
      if (tid == 0) {
        float S0 = 0.f;
        for (int k = 0; k < 8; ++k) S0 += sred[k];
        sred[17] = S0;
      }
      __syncthreads();
      float S = sred[17];
      float acc = 0.f;
      #pragma unroll
      for (int c = 0; c < 4; ++c) {
        float4 mv = *(const float4*)(sM + r*L_ATT + li*4 + c*128);
        float4 av = *(const float4*)(sal + li*4 + c*128);
        acc = dot4(mv, av, acc);
      }
      acc = rsum32(acc);
      if (li == 0) {
        float o = (acc / S) + sce[r] + scb[r];
        ovec[r0 + r] = fmaxf(o, 0.f);
      }
      __syncthreads();
      if (tid == 0) { __threadfence(); atomicAdd(arrB, 1u); }
    }
  } else if (bid < BID_V0) {
    // ---------------- G blocks (32): GRU cell, 8 h-elements each (24 rows of Wih/Whh) ----------------
    int g = bid - BID_G0; int j0 = g*8;
    float* sWi = (float*)smraw;          // [24][256]
    float* sWh = sWi + 24*H;             // [24][256]
    float* sh  = sWh + 24*H;             // 256
    float* so  = sh + H;                 // 256
    float* sgh = so + H;                 // 24
    float* sgi = sgh + 24;               // 24
    float* sbi = sgi + 24;               // 24
    float* sbh = sbi + 24;               // 24
    for (int idx = tid; idx < 24*H; idx += 512) {
      int r = idx >> 8, c = idx & 255;
      int grow = (r>>3)*H + j0 + (r&7);
      sWi[idx] = Wih[(size_t)grow*H + c];
      sWh[idx] = Whh[(size_t)grow*H + c];
    }
    if (tid < 24) { int grow = (tid>>3)*H + j0 + (tid&7); sbi[tid] = bih[grow]; sbh[tid] = bhh[grow]; }
    __syncthreads();
    int r = tid >> 4, li = tid & 15;   // 32 row-slots (use 24), 16 lanes each
    for (int s = 0; s < tlen; ++s) {
      if (tid == 0) s_stop = spin_ctr(arrC, (u32)NB_G*(u32)s, flagT);
      __syncthreads();
      if (s_stop) break;
      if (tid < 64) ((float4*)sh)[tid] = ((const float4*)(hdec + (s&1)*H))[tid];
      __syncthreads();
      if (r < 24) {
        float acc = 0.f;
        #pragma unroll
        for (int c = 0; c < 4; ++c) {
          float4 wv = *(const float4*)(sWh + r*H + li*4 + c*64);
          float4 hv = *(const float4*)(sh + li*4 + c*64);
          acc = dot4(wv, hv, acc);
        }
        acc = rsum16(acc);
        if (li == 0) sgh[r] = acc + sbh[r];
      }
      if (tid == 0) s_stop = spin_ctr(arrB, (u32)NB_B*(u32)(s+1), flagT);
      __syncthreads();
      if (s_stop) break;
      if (tid < 64) ((float4*)so)[tid] = ((const float4*)ovec)[tid];
      __syncthreads();
      if (r < 24) {
        float acc = 0.f;
        #pragma unroll
        for (int c = 0; c < 4; ++c) {
          float4 wv = *(const float4*)(sWi + r*H + li*4 + c*64);
          float4 ov = *(const float4*)(so + li*4 + c*64);
          acc = dot4(wv, ov, acc);
        }
        acc = rsum16(acc);
        if (li == 0) sgi[r] = acc + sbi[r];
      }
      __syncthreads();
      if (tid < 8) {
        int j = tid;
        float rg = sigf(sgi[j] + sgh[j]);
        float zg = sigf(sgi[8+j] + sgh[8+j]);
        float ng = tanhf(fmaf(rg, sgh[16+j], sgi[16+j]));
        float hold = sh[j0+j];
        float h2 = fmaf(zg, hold, (1.f-zg)*ng);
        hdec[((s+1)&1)*H + j0 + j] = h2;
      }
      __syncthreads();
      if (tid == 0) { __threadfence(); atomicAdd(arrC, 1u); atomicAdd(arrC2, 1u); }
    }
  } else {
    // ---------------- V blocks (175): logits + sumexp + argmax partials, RPB rows each ----------------
    int v = bid - BID_V0;
    int vstart = v * RPB;
    float* sh2 = (float*)smraw;                 // 256 floats
    double* swd = (double*)(smraw + 1024);      // [8]
    u64*    swk = (u64*)(smraw + 1024 + 64);    // [8]
    int idx0 = tid >> 1, s2 = tid & 1;
    int row0 = vstart + idx0;
    int row1 = row0 + 256;
    bool v0 = (idx0 < RPB) && (row0 < V);
    bool v1 = (idx0 + 256 < RPB) && (row1 < V);
    const float4* wp0 = (const float4*)(outW + (size_t)(v0 ? row0 : 0)*H) + s2*32;
    const float4* wp1 = (const float4*)(outW + (size_t)(v1 ? row1 : 0)*H) + s2*32;
    float ob0 = v0 ? outb[row0] : 0.f;
    float ob1 = v1 ? outb[row1] : 0.f;
    for (int s = 0; s < tlen; ++s) {
      if (tid == 0) s_stop = spin_ctr(arrC2, (u32)NB_G*(u32)(s+1), flagT);
      __syncthreads();
      if (s_stop) break;
      if (tid < 64) ((float4*)sh2)[tid] = ((const float4*)(hdec + ((s+1)&1)*H))[tid];
      __syncthreads();
      const float4* hp = ((const float4*)sh2) + s2*32;
      float a0 = 0.f, a1 = 0.f;
      #pragma unroll
      for (int k = 0; k < 32; ++k) { a0 = dot4(wp0[k], hp[k], a0); a1 = dot4(wp1[k], hp[k], a1); }
      a0 += __shfl_xor(a0, 1);
      a1 += __shfl_xor(a1, 1);
      double d = 0.0; u64 key = 0ull;
      if (s2 == 0) {
        int tgt = target[s];
        if (v0) {
          float lg = a0 + ob0;
          if (row0 == tgt) *ltgt_p = lg;
          d += (double)expf(lg);
          u64 k0 = ((u64)f2ord(lg) << 32) | (u64)(0xFFFFFFFFu - (u32)row0);
          if (k0 > key) key = k0;
        }
        if (v1) {
          float lg = a1 + ob1;
          if (row1 == tgt) *ltgt_p = lg;
          d += (double)expf(lg);
          u64 k1 = ((u64)f2ord(lg) << 32) | (u64)(0xFFFFFFFFu - (u32)row1);
          if (k1 > key) key = k1;
        }
      }
      d = rsumd64(d);
      key = rmaxk64(key);
      if (l == 0) { swd[w] = d; swk[w] = key; }
      __syncthreads();
      if (tid == 0) {
        double dd = 0.0; u64 kk = 0ull;
        for (int k = 0; k < 8; ++k) { dd += swd[k]; if (swk[k] > kk) kk = swk[k]; }
        psum[bid] = dd; pkey[bid] = kk;
        __threadfence(); atomicAdd(arrV, 1u);
      }
      __syncthreads();
    }
  }
}

// ---------------- host launcher ----------------
extern "C" void kernel_launch(void* const* d_in, const int* in_sizes, int n_in,
                              void* d_out, int out_size, void* d_ws, size_t ws_size,
                              hipStream_t stream) {
  const int*   in_tok  = (const int*)d_in[0];
  const int*   p_ilen  = (const int*)d_in[1];
  const int*   tgt_tok = (const int*)d_in[2];
  const int*   p_tlen  = (const int*)d_in[3];
  const float* enc_emb = (const float*)d_in[4];
  const float* dec_emb = (const float*)d_in[5];
  const float* eWih    = (const float*)d_in[6];
  const float* eWhh    = (const float*)d_in[7];
  const float* ebih    = (const float*)d_in[8];
  const float* ebhh    = (const float*)d_in[9];
  const float* dWih    = (const float*)d_in[10];
  const float* dWhh    = (const float*)d_in[11];
  const float* dbih    = (const float*)d_in[12];
  const float* dbhh    = (const float*)d_in[13];
  const float* attn_W  = (const float*)d_in[14];
  const float* attn_b  = (const float*)d_in[15];
  const float* comb_W  = (const float*)d_in[16];
  const float* comb_b  = (const float*)d_in[17];
  const float* outW    = (const float*)d_in[18];
  const float* outb    = (const float*)d_in[19];
  float* lossout = (float*)d_out;

  const int Tin = in_sizes[0];
  const int V   = in_sizes[18] / H;
  const int RPB = (V + NV - 1) / NV;   // 286 for V=50000

  size_t need = 16384 + (size_t)Tin*G3*4 + (size_t)L_ATT*H*4 + (size_t)H*L_ATT*4;
  if (ws_size < need) {
    hipLaunchKernelGGL(k_sentinel, dim3(1), dim3(64), 0, stream, lossout, -12345.f);
    return;
  }

  char* wsb = (char*)d_ws;
  u64*  flagT = (u64*)(wsb + 0);
  u32*  arrE  = (u32*)(wsb + 128);
  u32*  arrA  = (u32*)(wsb + 256);
  u32*  arrB  = (u32*)(wsb + 384);
  u32*  arrC  = (u32*)(wsb + 512);
  u32*  arrV  = (u32*)(wsb + 640);
  float* ltgt = (float*)(wsb + 768);
  u32*  arrC2 = (u32*)(wsb + 896);
  double* psum = (double*)(wsb + 1024);          // [256]
  u64*    pkey = (u64*)(wsb + 3072);             // [256]
  float*  henc = (float*)(wsb + 5120);           // [2][256]
  float*  hdec = (float*)(wsb + 7168);           // [2][256]
  float*  attnlog = (float*)(wsb + 9216);        // [512]
  float*  ovec    = (float*)(wsb + 11264);       // [256]
  float*  gi_buf  = (float*)(wsb + 16384);       // [Tin][768]
  float*  encout  = gi_buf + (size_t)Tin*G3;     // [512][256]
  float*  Mm      = encout + (size_t)L_ATT*H;    // [256][512]

  hipLaunchKernelGGL(k_init, dim3(64), dim3(256), 0, stream,
                     (u32*)wsb, 16384/4, encout, L_ATT*H);
  hipLaunchKernelGGL(k_gi, dim3(Tin), dim3(512), 0, stream,
                     in_tok, p_ilen, enc_emb, eWih, ebih, gi_buf);
  hipLaunchKernelGGL(k_enc, dim3(16), dim3(512), (48*H + H + 48 + 48)*4, stream,
                     p_ilen, eWhh, ebhh, gi_buf, henc, encout, arrE);
  hipLaunchKernelGGL(k_m, dim3(257), dim3(512), 0, stream,
                     p_ilen, comb_W, encout, Mm, henc, hdec);
  hipLaunchKernelGGL(k_dec, dim3(NBLK), dim3(512), 52480, stream,
                     p_tlen, tgt_tok, dec_emb, attn_W, attn_b, comb_W, comb_b,
                     dWih, dWhh, dbih, dbhh, outW, outb, Mm,
                     hdec, attnlog, ovec, psum, pkey, ltgt,
                     flagT, arrA, arrB, arrC, arrC2, arrV, lossout, V, RPB);
}

// Round 9
// 10491.458 us; speedup vs baseline: 1.5299x; 1.5299x over previous
//
#include <hip/hip_runtime.h>
#include <stdint.h>

typedef unsigned int u32;
typedef unsigned long long u64;

#define SCOPE_AGENT __HIP_MEMORY_SCOPE_AGENT

#define H 256
#define L_ATT 512
#define G3 768
#define EOS_TOK 1

// role layout: 1 ctrl + 16 A + 8 B + 32 G + 196 V = 253 blocks (<=256 CUs)
#define NB_A 16
#define NB_B 8
#define NB_G 32
#define NVB  196
#define BID_A0 1
#define BID_B0 (BID_A0 + NB_A)   /* 17 */
#define BID_G0 (BID_B0 + NB_B)   /* 25 */
#define BID_V0 (BID_G0 + NB_G)   /* 57 */
#define NBLK (BID_V0 + NVB)      /* 253 */

#define STOPBIT 0x80000000ull
#define SPIN_LIMIT 50000000ull   /* ~0.5s @100MHz: finite bail-out on any stall */

// ---------------- atomics helpers ----------------
__device__ __forceinline__ u32 ld_rlx(u32* p){ return __hip_atomic_load(p, __ATOMIC_RELAXED, SCOPE_AGENT); }
__device__ __forceinline__ u32 ld_acq(u32* p){ return __hip_atomic_load(p, __ATOMIC_ACQUIRE, SCOPE_AGENT); }
__device__ __forceinline__ u64 ld64_rlx(u64* p){ return __hip_atomic_load(p, __ATOMIC_RELAXED, SCOPE_AGENT); }
__device__ __forceinline__ u64 ld64_acq(u64* p){ return __hip_atomic_load(p, __ATOMIC_ACQUIRE, SCOPE_AGENT); }
__device__ __forceinline__ void st64_rel(u64* p, u64 v){ __hip_atomic_store(p, v, __ATOMIC_RELEASE, SCOPE_AGENT); }
__device__ __forceinline__ void st32_rel(u32* p, u32 v){ __hip_atomic_store(p, v, __ATOMIC_RELEASE, SCOPE_AGENT); }
__device__ __forceinline__ float ldf_rlx(float* p){ return __hip_atomic_load(p, __ATOMIC_RELAXED, SCOPE_AGENT); }
__device__ __forceinline__ void stf_rlx(float* p, float v){ __hip_atomic_store(p, v, __ATOMIC_RELAXED, SCOPE_AGENT); }

// multi-poll wait: threads tid<n poll seqbase[tid*16] >= target (64B-strided slots, no RMW).
// tid0 additionally watches flagp for STOPBIT. On abort/timeout sets *s_abort (terminal).
__device__ __forceinline__ void wait_group(u32* seqbase, int n, u32 target,
                                           u64* flagp, volatile int* s_abort, int tid) {
  if (tid < n) {
    u32* myp = seqbase + (tid << 4);
    if (ld_rlx(myp) < target) {
      u64 t0 = __builtin_amdgcn_s_memrealtime();
      u32 k = 0;
      for (;;) {
        if (ld_rlx(myp) >= target) break;
        if (*s_abort) break;
        ++k;
        if (tid == 0 && flagp && ((k & 63u) == 0u)) {
          u64 f = ld64_rlx(flagp);
          if (f & STOPBIT) { (void)ld64_acq(flagp); *s_abort = 1; break; }
        }
        if ((k & 2047u) == 0u) {
          if (__builtin_amdgcn_s_memrealtime() - t0 > SPIN_LIMIT) { *s_abort = 2; break; }
        }
        __builtin_amdgcn_s_sleep(1);
      }
    }
    (void)ld_acq(myp);  // acquire: orders + invalidates L1 for this CU
  }
  __syncthreads();
}

// spin until flag step >= step (or stop/timeout); returns flag value (timeout -> STOPBIT)
__device__ __forceinline__ u64 spin_flag(u64* flagp, u32 step) {
  u64 t0 = __builtin_amdgcn_s_memrealtime();
  u32 k = 0;
  for (;;) {
    u64 f = ld64_rlx(flagp);
    if ((u32)(f >> 32) >= step || (f & STOPBIT)) { (void)ld64_acq(flagp); return f; }
    ++k;
    if ((k & 1023u) == 0u) {
      if (__builtin_amdgcn_s_memrealtime() - t0 > SPIN_LIMIT) return STOPBIT;
    }
    __builtin_amdgcn_s_sleep(1);
  }
}

// ---------------- math helpers ----------------
__device__ __forceinline__ float sigf(float x){ return 1.f/(1.f + expf(-x)); }
__device__ __forceinline__ float dot4(float4 a, float4 b, float acc){
  acc = fmaf(a.x,b.x,acc); acc = fmaf(a.y,b.y,acc); acc = fmaf(a.z,b.z,acc); return fmaf(a.w,b.w,acc);
}
__device__ __forceinline__ u32 f2ord(float x){
  u32 b = __float_as_uint(x); return (b & 0x80000000u) ? ~b : (b | 0x80000000u);
}
__device__ __forceinline__ float rsum64(float v){
  v += __shfl_xor(v,1); v += __shfl_xor(v,2); v += __shfl_xor(v,4);
  v += __shfl_xor(v,8); v += __shfl_xor(v,16); v += __shfl_xor(v,32); return v;
}
__device__ __forceinline__ float rsum16(float v){
  v += __shfl_xor(v,1); v += __shfl_xor(v,2); v += __shfl_xor(v,4); v += __shfl_xor(v,8); return v;
}
__device__ __forceinline__ float rmaxf64(float v){
  v = fmaxf(v,__shfl_xor(v,1)); v = fmaxf(v,__shfl_xor(v,2)); v = fmaxf(v,__shfl_xor(v,4));
  v = fmaxf(v,__shfl_xor(v,8)); v = fmaxf(v,__shfl_xor(v,16)); v = fmaxf(v,__shfl_xor(v,32)); return v;
}
__device__ __forceinline__ double rsumd64(double v){
  v += __shfl_xor(v,1); v += __shfl_xor(v,2); v += __shfl_xor(v,4);
  v += __shfl_xor(v,8); v += __shfl_xor(v,16); v += __shfl_xor(v,32); return v;
}
__device__ __forceinline__ u64 rmaxk64(u64 k){
  u64 o;
  o=__shfl_xor(k,1);  k=k>o?k:o; o=__shfl_xor(k,2);  k=k>o?k:o;
  o=__shfl_xor(k,4);  k=k>o?k:o; o=__shfl_xor(k,8);  k=k>o?k:o;
  o=__shfl_xor(k,16); k=k>o?k:o; o=__shfl_xor(k,32); k=k>o?k:o;
  return k;
}

// ---------------- K0: init workspace head + encout ----------------
__global__ __launch_bounds__(256) void k_init(u32* head, int nhead, float* encout, int nenc) {
  int i = blockIdx.x*blockDim.x + threadIdx.x;
  int st = gridDim.x*blockDim.x;
  for (int k = i; k < nhead; k += st) head[k] = 0u;
  for (int k = i; k < nenc; k += st) encout[k] = 0.f;
}

__global__ __launch_bounds__(64) void k_sentinel(float* out, float v) {
  if (threadIdx.x == 0) out[0] = v;
}

// ---------------- K1: encoder gi GEMM (all steps parallel) ----------------
__global__ __launch_bounds__(512) void k_gi(const int* __restrict__ in_tok, const int* __restrict__ p_ilen,
                                            const float* __restrict__ emb, const float* __restrict__ Wih,
                                            const float* __restrict__ bih, float* __restrict__ gi_buf) {
  int t = blockIdx.x;
  if (t >= p_ilen[0]) return;
  __shared__ float se[H];
  int tid = threadIdx.x;
  if (tid < 64) ((float4*)se)[tid] = ((const float4*)(emb + (size_t)in_tok[t]*H))[tid];
  __syncthreads();
  int w = tid >> 6, l = tid & 63;
  float4 hv = ((const float4*)se)[l];
  for (int rr = 0; rr < 96; ++rr) {
    int row = rr*8 + w;
    float4 wv = ((const float4*)(Wih + (size_t)row*H))[l];
    float acc = dot4(wv, hv, 0.f);
    acc = rsum64(acc);
    if (l == 0) gi_buf[(size_t)t*G3 + row] = acc + bih[row];
  }
}

// ---------------- K2: encoder sequential scan, 16 blocks, seq-slot synced (LDS 50.5KB < 64KB) ----------------
__global__ __launch_bounds__(512) void k_enc(const int* __restrict__ p_ilen, const float* __restrict__ Whh,
                                             const float* __restrict__ bhh, const float* __restrict__ gi_buf,
                                             float* henc /*[2][H]*/, float* encout, u32* eseq) {
  extern __shared__ char smraw[];
  float* sW  = (float*)smraw;        // [48][256]
  float* sh  = sW + 48*H;            // 256
  float* sgh = sh + H;               // 48
  float* sbh = sgh + 48;             // 48
  __shared__ int s_abort;
  int e = blockIdx.x, tid = threadIdx.x;
  int j0 = e*16;
  int ilen = p_ilen[0];
  if (tid == 0) s_abort = 0;
  for (int idx = tid; idx < 48*H; idx += 512) {
    int r = idx >> 8, c = idx & 255;
    int grow = (r>>4)*H + j0 + (r&15);
    sW[idx] = Whh[(size_t)grow*H + c];
  }
  if (tid < 48) { int grow = (tid>>4)*H + j0 + (tid&15); sbh[tid] = bhh[grow]; }
  __syncthreads();
  int w = tid>>6, l = tid&63;
  for (int t = 0; t < ilen; ++t) {
    wait_group(eseq, 16, (u32)t, nullptr, &s_abort, tid);
    if (s_abort) break;
    if (tid < 64) ((float4*)sh)[tid] = ((const float4*)(henc + (t&1)*H))[tid];
    __syncthreads();
    for (int rr = 0; rr < 6; ++rr) {
      int r = rr*8 + w;
      float4 wv = ((const float4*)(sW + r*H))[l];
      float4 hv = ((const float4*)sh)[l];
      float acc = dot4(wv, hv, 0.f);
      acc = rsum64(acc);
      if (l == 0) sgh[r] = acc + sbh[r];
    }
    __syncthreads();
    if (tid < 16) {
      int j = tid;
      const float* gi = gi_buf + (size_t)t*G3;
      float gir = gi[j0+j], giz = gi[H+j0+j], gin = gi[2*H+j0+j];
      float rg = sigf(gir + sgh[j]);
      float zg = sigf(giz + sgh[16+j]);
      float ng = tanhf(fmaf(rg, sgh[32+j], gin));
      float hold = sh[j0+j];
      float h2 = fmaf(zg, hold, (1.f-zg)*ng);
      henc[((t+1)&1)*H + j0 + j] = h2;
      encout[(size_t)t*H + j0 + j] = h2;
    }
    __syncthreads();
    if (tid == 0) { __threadfence(); st32_rel(eseq + (e<<4), (u32)(t+1)); }
  }
}

// ---------------- K3: M = comb_W[:,256:] @ encout^T ; copy final enc h -> hdec buf0 ----------------
__global__ __launch_bounds__(512) void k_m(const int* __restrict__ p_ilen, const float* __restrict__ combW,
                                           const float* __restrict__ encout, float* __restrict__ Mm,
                                           const float* __restrict__ henc, float* __restrict__ hdec) {
  int i = blockIdx.x, tid = threadIdx.x;
  if (i == 256) {
    int ilen = p_ilen[0];
    if (tid < H) hdec[tid] = henc[(ilen&1)*H + tid];
    return;
  }
  __shared__ float sw[H];
  if (tid < 64) ((float4*)sw)[tid] = ((const float4*)(combW + (size_t)i*(2*H) + H))[tid];
  __syncthreads();
  int w = tid>>6, l = tid&63;
  float4 wv = ((const float4*)sw)[l];
  for (int lr = 0; lr < 64; ++lr) {
    int row = lr*8 + w; // 0..511
    float4 ev = ((const float4*)(encout + (size_t)row*H))[l];
    float acc = dot4(wv, ev, 0.f);
    acc = rsum64(acc);
    if (l == 0) Mm[(size_t)i*L_ATT + row] = acc;
  }
}

// ---------------- K4: persistent decoder. ALL weights register-resident; LDS <= 3.5KB ----------------
__global__ __launch_bounds__(512, 2) void k_dec(
    const int* p_tlen, const int* target,
    const float* __restrict__ dec_emb, const float* __restrict__ attn_W,
    const float* __restrict__ attn_b, const float* __restrict__ comb_W,
    const float* __restrict__ comb_b, const float* __restrict__ Wih,
    const float* __restrict__ Whh, const float* __restrict__ bih,
    const float* __restrict__ bhh, const float* __restrict__ outW,
    const float* __restrict__ outb, const float* __restrict__ Mm,
    float* hdec, float* attnlog, float* ovec,
    double* psum, u64* pkey, float* ltgt_p,
    u64* flagT, u32* aseq, u32* bseq, u32* gseq, u32* vseq,
    float* lossout, int Vv)
{
  extern __shared__ char smraw[];
  __shared__ u64 s_flag;
  __shared__ int s_abort;
  int bid = blockIdx.x, tid = threadIdx.x;
  int tlen = p_tlen[0];
  int w = tid >> 6, l = tid & 63;
  if (tid == 0) s_abort = 0;
  __syncthreads();

  if (bid == 0) {
    // ---------------- control: reduce 196 partials, loss, argmax, publish token ----------------
    double* rd = (double*)smraw;          // [8]
    u64*    rk = (u64*)(smraw + 64);      // [8]
    double loss = 0.0;
    if (tlen <= 0) {
      if (tid == 0) { lossout[0] = 0.f; __threadfence(); st64_rel(flagT, (((u64)1)<<32) | STOPBIT); }
      return;
    }
    for (int s = 0; s < tlen; ++s) {
      wait_group(vseq, NVB, (u32)(s+1), nullptr, &s_abort, tid);
      if (s_abort) {
        if (tid == 0) { lossout[0] = -777.f; __threadfence(); st64_rel(flagT, (((u64)(s+1))<<32) | STOPBIT); }
        break;
      }
      double pd = 0.0; u64 pk = 0ull;
      if (tid < NVB) { pd = psum[tid]; pk = pkey[tid]; }
      pd = rsumd64(pd); pk = rmaxk64(pk);
      if (l == 0) { rd[w] = pd; rk[w] = pk; }
      __syncthreads();
      __shared__ int s_stop;
      if (tid == 0) {
        double ssum = 0.0; u64 key = 0ull;
        for (int k = 0; k < 8; ++k) { ssum += rd[k]; if (rk[k] > key) key = rk[k]; }
        int top = (int)(0xFFFFFFFFu - (u32)(key & 0xFFFFFFFFull));
        float lt = ldf_rlx(ltgt_p);
        loss += log(ssum) - (double)lt;      // -logp[tgt] = lse - logit[tgt]
        bool fin = (top == EOS_TOK) || (s == tlen - 1);
        if (fin) {
          lossout[0] = (float)loss;
          __threadfence();
          st64_rel(flagT, (((u64)(s+1))<<32) | STOPBIT);
        } else {
          st64_rel(flagT, (((u64)(s+1))<<32) | (u64)(u32)top);
        }
        s_stop = fin ? 1 : 0;
      }
      __syncthreads();
      if (s_stop) break;
    }
  } else if (bid < BID_B0) {
    // ---------------- A blocks (16): attn logits, 32 rows each; attn_W in registers ----------------
    int a = bid - BID_A0; int r0 = a*32;
    float* scat = (float*)smraw;          // [512] = [emb | h]
    float* sab  = scat + L_ATT;           // [32]
    int r = tid >> 4, li = tid & 15;      // 32 rows, 16 lanes/row, 32 cols/lane
    float4 aw[8];
    {
      const float4* src = (const float4*)(attn_W + (size_t)(r0 + r)*L_ATT) + li*8;
      #pragma unroll
      for (int k = 0; k < 8; ++k) aw[k] = src[k];
    }
    if (tid < 32) sab[tid] = attn_b[r0 + tid];
    __syncthreads();
    for (int s = 0; s < tlen; ++s) {
      if (tid == 0) s_flag = spin_flag(flagT, (u32)s);
      __syncthreads();
      u64 f = s_flag;
      if (f & STOPBIT) break;
      int tok = (int)((u32)f & 0x7FFFFFFFu);
      // flag(s) transitively implies h(s) published (ctrl<-V(s-1)<-gseq>=s)
      if (tid < 64)       ((float4*)scat)[tid]      = ((const float4*)(dec_emb + (size_t)tok*H))[tid];
      else if (tid < 128) ((float4*)(scat+H))[tid-64] = ((const float4*)(hdec + (s&1)*H))[tid-64];
      __syncthreads();
      const float4* sc = ((const float4*)scat) + li*8;
      float acc = 0.f;
      #pragma unroll
      for (int k = 0; k < 8; ++k) acc = dot4(aw[k], sc[k], acc);
      acc = rsum16(acc);
      if (li == 0) attnlog[r0 + r] = acc + sab[r];
      __syncthreads();
      if (tid == 0) { __threadfence(); st32_rel(aseq + (a<<4), (u32)(s+1)); }
    }
  } else if (bid < BID_G0) {
    // ---------------- B blocks (8): softmax + o = relu(W1@emb + M@attn/S + b); W1,M in registers ----------------
    int b = bid - BID_B0; int r0 = b*32;
    float* se  = (float*)smraw;          // 256
    float* sal = se + H;                 // 512
    float* sred= sal + L_ATT;            // 32
    float* sce = sred + 32;              // 32
    float* scb = sce + 32;               // 32
    int r = tid >> 4, li = tid & 15;     // 32 rows, 16 lanes/row
    float4 w1[4];   // comb_W[:, :256], 16 cols/lane
    float4 mw[8];   // M rows, 32 cols/lane
    {
      const float4* s1 = (const float4*)(comb_W + (size_t)(r0 + r)*(2*H)) + li*4;
      #pragma unroll
      for (int k = 0; k < 4; ++k) w1[k] = s1[k];
      const float4* s2 = (const float4*)(Mm + (size_t)(r0 + r)*L_ATT) + li*8;
      #pragma unroll
      for (int k = 0; k < 8; ++k) mw[k] = s2[k];
    }
    if (tid < 32) scb[tid] = comb_b[r0 + tid];
    __syncthreads();
    for (int s = 0; s < tlen; ++s) {
      if (tid == 0) s_flag = spin_flag(flagT, (u32)s);
      __syncthreads();
      u64 f = s_flag;
      if (f & STOPBIT) break;
      int tok = (int)((u32)f & 0x7FFFFFFFu);
      if (tid < 64) ((float4*)se)[tid] = ((const float4*)(dec_emb + (size_t)tok*H))[tid];
      __syncthreads();
      float ce = 0.f;
      {
        const float4* ee = ((const float4*)se) + li*4;
        #pragma unroll
        for (int k = 0; k < 4; ++k) ce = dot4(w1[k], ee[k], ce);
        ce = rsum16(ce);
      }
      if (li == 0) sce[r] = ce;
      wait_group(aseq, NB_A, (u32)(s+1), flagT, &s_abort, tid);
      if (s_abort) break;
      // softmax over 512 logits (one per thread)
      float x = attnlog[tid];
      float wm = rmaxf64(x);
      if (l == 0) sred[w] = wm;
      __syncthreads();
      if (tid == 0) {
        float m0 = sred[0];
        for (int k = 1; k < 8; ++k) m0 = fmaxf(m0, sred[k]);
        sred[16] = m0;
      }
      __syncthreads();
      float mx = sred[16];
      float e = expf(x - mx);
      sal[tid] = e;
      float wsum = rsum64(e);
      if (l == 0) sred[w] = wsum;
      __syncthreads();
      if (tid == 0) {
        float S0 = 0.f;
        for (int k = 0; k < 8; ++k) S0 += sred[k];
        sred[17] = S0;
      }
      __syncthreads();
      float S = sred[17];
      float acc = 0.f;
      {
        const float4* av = ((const float4*)sal) + li*8;
        #pragma unroll
        for (int k = 0; k < 8; ++k) acc = dot4(mw[k], av[k], acc);
        acc = rsum16(acc);
      }
      if (li == 0) {
        float o = (acc / S) + sce[r] + scb[r];
        ovec[r0 + r] = fmaxf(o, 0.f);
      }
      __syncthreads();
      if (tid == 0) { __threadfence(); st32_rel(bseq + (b<<4), (u32)(s+1)); }
    }
  } else if (bid < BID_V0) {
    // ---------------- G blocks (32): GRU cell, 8 h-elems each; Wih/Whh in registers ----------------
    int g = bid - BID_G0; int j0 = g*8;
    float* sh  = (float*)smraw;          // 256
    float* so  = sh + H;                 // 256
    float* sgh = so + H;                 // 24
    float* sgi = sgh + 24;               // 24
    float* sbi = sgi + 24;               // 24
    float* sbh = sbi + 24;               // 24
    int r = tid >> 4, li = tid & 15;     // 32 row-slots (use 24), 16 lanes, 16 cols/lane
    float4 wih[4], whh[4];
    if (r < 24) {
      int grow = (r>>3)*H + j0 + (r&7);
      const float4* s1 = (const float4*)(Wih + (size_t)grow*H) + li*4;
      const float4* s2 = (const float4*)(Whh + (size_t)grow*H) + li*4;
      #pragma unroll
      for (int k = 0; k < 4; ++k) { wih[k] = s1[k]; whh[k] = s2[k]; }
    }
    if (tid < 24) { int grow = (tid>>3)*H + j0 + (tid&7); sbi[tid] = bih[grow]; sbh[tid] = bhh[grow]; }
    __syncthreads();
    for (int s = 0; s < tlen; ++s) {
      wait_group(gseq, NB_G, (u32)s, flagT, &s_abort, tid);   // h(s) ready
      if (s_abort) break;
      if (tid < 64) ((float4*)sh)[tid] = ((const float4*)(hdec + (s&1)*H))[tid];
      __syncthreads();
      if (r < 24) {
        const float4* hv = ((const float4*)sh) + li*4;
        float acc = 0.f;
        #pragma unroll
        for (int k = 0; k < 4; ++k) acc = dot4(whh[k], hv[k], acc);
        acc = rsum16(acc);
        if (li == 0) sgh[r] = acc + sbh[r];
      }
      wait_group(bseq, NB_B, (u32)(s+1), flagT, &s_abort, tid);
      if (s_abort) break;
      if (tid < 64) ((float4*)so)[tid] = ((const float4*)ovec)[tid];
      __syncthreads();
      if (r < 24) {
        const float4* ov = ((const float4*)so) + li*4;
        float acc = 0.f;
        #pragma unroll
        for (int k = 0; k < 4; ++k) acc = dot4(wih[k], ov[k], acc);
        acc = rsum16(acc);
        if (li == 0) sgi[r] = acc + sbi[r];
      }
      __syncthreads();
      if (tid < 8) {
        int j = tid;
        float rg = sigf(sgi[j] + sgh[j]);
        float zg = sigf(sgi[8+j] + sgh[8+j]);
        float ng = tanhf(fmaf(rg, sgh[16+j], sgi[16+j]));
        float hold = sh[j0+j];
        float h2 = fmaf(zg, hold, (1.f-zg)*ng);
        hdec[((s+1)&1)*H + j0 + j] = h2;
      }
      __syncthreads();
      if (tid == 0) { __threadfence(); st32_rel(gseq + (g<<4), (u32)(s+1)); }
    }
  } else {
    // ---------------- V blocks (196): out_W REGISTER-RESIDENT. 256 rows/block, 2 thr/row ----------------
    int v = bid - BID_V0;
    float* sh2 = (float*)smraw;                 // 256 floats
    double* swd = (double*)(smraw + 1024);      // [8]
    u64*    swk = (u64*)(smraw + 1024 + 64);    // [8]
    int rowhalf = tid >> 1, s2 = tid & 1;
    int row = v*256 + rowhalf;
    bool valid = (row < Vv);
    const float4* wsrc = (const float4*)(outW + (size_t)(valid ? row : 0)*H) + s2*32;
    float4 wreg[32];
    #pragma unroll
    for (int k = 0; k < 32; ++k) wreg[k] = wsrc[k];   // 128 VGPRs of weights
    float ob = valid ? outb[row] : 0.f;
    for (int s = 0; s < tlen; ++s) {
      wait_group(gseq, NB_G, (u32)(s+1), flagT, &s_abort, tid);  // h(s+1) ready
      if (s_abort) break;
      if (tid < 64) ((float4*)sh2)[tid] = ((const float4*)(hdec + ((s+1)&1)*H))[tid];
      __syncthreads();
      const float4* hp = ((const float4*)sh2) + s2*32;
      float acc = 0.f;
      #pragma unroll
      for (int k = 0; k < 32; ++k) acc = dot4(wreg[k], hp[k], acc);
      acc += __shfl_xor(acc, 1);
      float logit = acc + ob;
      double d = 0.0; u64 key = 0ull;
      if (valid && s2 == 0) {
        if (row == target[s]) stf_rlx(ltgt_p, logit);
        d = (double)expf(logit);
        key = ((u64)f2ord(logit) << 32) | (u64)(0xFFFFFFFFu - (u32)row);
      }
      d = rsumd64(d);
      key = rmaxk64(key);
      if (l == 0) { swd[w] = d; swk[w] = key; }
      __syncthreads();
      if (tid == 0) {
        double dd = 0.0; u64 kk = 0ull;
        for (int k = 0; k < 8; ++k) { dd += swd[k]; if (swk[k] > kk) kk = swk[k]; }
        psum[v] = dd; pkey[v] = kk;
        __threadfence();
        st32_rel(vseq + (v<<4), (u32)(s+1));
      }
      // next wait_group's __syncthreads orders reuse of sh2/swd
    }
  }
}

// ---------------- host launcher ----------------
extern "C" void kernel_launch(void* const* d_in, const int* in_sizes, int n_in,
                              void* d_out, int out_size, void* d_ws, size_t ws_size,
                              hipStream_t stream) {
  const int*   in_tok  = (const int*)d_in[0];
  const int*   p_ilen  = (const int*)d_in[1];
  const int*   tgt_tok = (const int*)d_in[2];
  const int*   p_tlen  = (const int*)d_in[3];
  const float* enc_emb = (const float*)d_in[4];
  const float* dec_emb = (const float*)d_in[5];
  const float* eWih    = (const float*)d_in[6];
  const float* eWhh    = (const float*)d_in[7];
  const float* ebih    = (const float*)d_in[8];
  const float* ebhh    = (const float*)d_in[9];
  const float* dWih    = (const float*)d_in[10];
  const float* dWhh    = (const float*)d_in[11];
  const float* dbih    = (const float*)d_in[12];
  const float* dbhh    = (const float*)d_in[13];
  const float* attn_W  = (const float*)d_in[14];
  const float* attn_b  = (const float*)d_in[15];
  const float* comb_W  = (const float*)d_in[16];
  const float* comb_b  = (const float*)d_in[17];
  const float* outW    = (const float*)d_in[18];
  const float* outb    = (const float*)d_in[19];
  float* lossout = (float*)d_out;

  const int Tin = in_sizes[0];
  const int V   = in_sizes[18] / H;

  if ((V + 255) / 256 > NVB) {
    hipLaunchKernelGGL(k_sentinel, dim3(1), dim3(64), 0, stream, lossout, -12346.f);
    return;
  }
  size_t need = 32768 + (size_t)Tin*G3*4 + (size_t)L_ATT*H*4 + (size_t)H*L_ATT*4;
  if (ws_size < need) {
    hipLaunchKernelGGL(k_sentinel, dim3(1), dim3(64), 0, stream, lossout, -12345.f);
    return;
  }

  char* wsb = (char*)d_ws;
  u64*  flagT = (u64*)(wsb + 0);
  float* ltgt = (float*)(wsb + 128);
  float* henc = (float*)(wsb + 256);             // [2][256]
  float* hdec = (float*)(wsb + 2560);            // [2][256]
  float* attnlog = (float*)(wsb + 4608);         // [512]
  float* ovec    = (float*)(wsb + 6656);         // [256]
  u32*  eseq  = (u32*)(wsb + 8192);              // 16 slots x 64B
  u32*  aseq  = (u32*)(wsb + 9216);              // 16 slots
  u32*  bseq  = (u32*)(wsb + 10240);             // 8 slots
  u32*  gseq  = (u32*)(wsb + 10752);             // 32 slots
  u32*  vseq  = (u32*)(wsb + 12800);             // 196 slots (12.25KB)
  double* psum = (double*)(wsb + 25600);         // [196]
  u64*    pkey = (u64*)(wsb + 27200);            // [196]
  float*  gi_buf  = (float*)(wsb + 32768);       // [Tin][768]
  float*  encout  = gi_buf + (size_t)Tin*G3;     // [512][256]
  float*  Mm      = encout + (size_t)L_ATT*H;    // [256][512]

  hipLaunchKernelGGL(k_init, dim3(64), dim3(256), 0, stream,
                     (u32*)wsb, 32768/4, encout, L_ATT*H);
  hipLaunchKernelGGL(k_gi, dim3(Tin), dim3(512), 0, stream,
                     in_tok, p_ilen, enc_emb, eWih, ebih, gi_buf);
  hipLaunchKernelGGL(k_enc, dim3(16), dim3(512), (48*H + H + 48 + 48)*4, stream,
                     p_ilen, eWhh, ebhh, gi_buf, henc, encout, eseq);
  hipLaunchKernelGGL(k_m, dim3(257), dim3(512), 0, stream,
                     p_ilen, comb_W, encout, Mm, henc, hdec);
  // dynamic LDS now tiny (max role need ~3.5KB) -> well under the 64KB per-block launch limit
  hipLaunchKernelGGL(k_dec, dim3(NBLK), dim3(512), 4096, stream,
                     p_tlen, tgt_tok, dec_emb, attn_W, attn_b, comb_W, comb_b,
                     dWih, dWhh, dbih, dbhh, outW, outb, Mm,
                     hdec, attnlog, ovec, psum, pkey, ltgt,
                     flagT, aseq, bseq, gseq, vseq, lossout, V);
}

// Round 10
// 10487.096 us; speedup vs baseline: 1.5305x; 1.0004x over previous
//
#include <hip/hip_runtime.h>
#include <stdint.h>

typedef unsigned int u32;
typedef unsigned long long u64;

#define SCOPE_AGENT __HIP_MEMORY_SCOPE_AGENT

#define H 256
#define L_ATT 512
#define G3 768
#define EOS_TOK 1

// role layout: 1 ctrl + 16 A + 8 B + 32 G + 196 V = 253 blocks (<=256 CUs)
#define NB_A 16
#define NB_B 8
#define NB_G 32
#define NVB  196
#define BID_A0 1
#define BID_B0 (BID_A0 + NB_A)   /* 17 */
#define BID_G0 (BID_B0 + NB_B)   /* 25 */
#define BID_V0 (BID_G0 + NB_G)   /* 57 */
#define NBLK (BID_V0 + NVB)      /* 253 */

#define STOPBIT 0x80000000ull
#define SPIN_LIMIT 50000000ull   /* ~0.5s @100MHz: finite bail-out on any stall */

// ---------------- atomics helpers ----------------
__device__ __forceinline__ u32 ld_rlx(u32* p){ return __hip_atomic_load(p, __ATOMIC_RELAXED, SCOPE_AGENT); }
__device__ __forceinline__ u32 ld_acq(u32* p){ return __hip_atomic_load(p, __ATOMIC_ACQUIRE, SCOPE_AGENT); }
__device__ __forceinline__ u64 ld64_rlx(u64* p){ return __hip_atomic_load(p, __ATOMIC_RELAXED, SCOPE_AGENT); }
__device__ __forceinline__ u64 ld64_acq(u64* p){ return __hip_atomic_load(p, __ATOMIC_ACQUIRE, SCOPE_AGENT); }
__device__ __forceinline__ void st64_rel(u64* p, u64 v){ __hip_atomic_store(p, v, __ATOMIC_RELEASE, SCOPE_AGENT); }
__device__ __forceinline__ void st32_rel(u32* p, u32 v){ __hip_atomic_store(p, v, __ATOMIC_RELEASE, SCOPE_AGENT); }
__device__ __forceinline__ float ldf_rlx(float* p){ return __hip_atomic_load(p, __ATOMIC_RELAXED, SCOPE_AGENT); }
__device__ __forceinline__ void stf_rlx(float* p, float v){ __hip_atomic_store(p, v, __ATOMIC_RELAXED, SCOPE_AGENT); }

// Pin a float4 into VGPRs: the empty asm makes the value opaque, so the
// compiler CANNOT rematerialize the originating global load inside the loop.
// (Round-9 evidence: VGPR_Count=88 => wreg[32] was re-loaded from L3 every
// step, ~12us/step of L2/L3 traffic invisible in FETCH_SIZE.)
__device__ __forceinline__ void pin4(float4 &v){
  asm volatile("" : "+v"(v.x), "+v"(v.y), "+v"(v.z), "+v"(v.w));
}

// multi-poll wait: threads tid<n poll seqbase[tid*16] >= target (64B-strided slots, no RMW).
// tid0 additionally watches flagp for STOPBIT. On abort/timeout sets *s_abort (terminal).
__device__ __forceinline__ void wait_group(u32* seqbase, int n, u32 target,
                                           u64* flagp, volatile int* s_abort, int tid) {
  if (tid < n) {
    u32* myp = seqbase + (tid << 4);
    if (ld_rlx(myp) < target) {
      u64 t0 = __builtin_amdgcn_s_memrealtime();
      u32 k = 0;
      for (;;) {
        if (ld_rlx(myp) >= target) break;
        if (*s_abort) break;
        ++k;
        if (tid == 0 && flagp && ((k & 63u) == 0u)) {
          u64 f = ld64_rlx(flagp);
          if (f & STOPBIT) { (void)ld64_acq(flagp); *s_abort = 1; break; }
        }
        if ((k & 2047u) == 0u) {
          if (__builtin_amdgcn_s_memrealtime() - t0 > SPIN_LIMIT) { *s_abort = 2; break; }
        }
        __builtin_amdgcn_s_sleep(1);
      }
    }
    (void)ld_acq(myp);  // acquire: orders + invalidates L1 for this CU
  }
  __syncthreads();
}

// spin until flag step >= step (or stop/timeout); returns flag value (timeout -> STOPBIT)
__device__ __forceinline__ u64 spin_flag(u64* flagp, u32 step) {
  u64 t0 = __builtin_amdgcn_s_memrealtime();
  u32 k = 0;
  for (;;) {
    u64 f = ld64_rlx(flagp);
    if ((u32)(f >> 32) >= step || (f & STOPBIT)) { (void)ld64_acq(flagp); return f; }
    ++k;
    if ((k & 1023u) == 0u) {
      if (__builtin_amdgcn_s_memrealtime() - t0 > SPIN_LIMIT) return STOPBIT;
    }
    __builtin_amdgcn_s_sleep(1);
  }
}

// ---------------- math helpers ----------------
__device__ __forceinline__ float sigf(float x){ return 1.f/(1.f + expf(-x)); }
__device__ __forceinline__ float dot4(float4 a, float4 b, float acc){
  acc = fmaf(a.x,b.x,acc); acc = fmaf(a.y,b.y,acc); acc = fmaf(a.z,b.z,acc); return fmaf(a.w,b.w,acc);
}
__device__ __forceinline__ u32 f2ord(float x){
  u32 b = __float_as_uint(x); return (b & 0x80000000u) ? ~b : (b | 0x80000000u);
}
__device__ __forceinline__ float rsum64(float v){
  v += __shfl_xor(v,1); v += __shfl_xor(v,2); v += __shfl_xor(v,4);
  v += __shfl_xor(v,8); v += __shfl_xor(v,16); v += __shfl_xor(v,32); return v;
}
__device__ __forceinline__ float rsum16(float v){
  v += __shfl_xor(v,1); v += __shfl_xor(v,2); v += __shfl_xor(v,4); v += __shfl_xor(v,8); return v;
}
__device__ __forceinline__ float rmaxf64(float v){
  v = fmaxf(v,__shfl_xor(v,1)); v = fmaxf(v,__shfl_xor(v,2)); v = fmaxf(v,__shfl_xor(v,4));
  v = fmaxf(v,__shfl_xor(v,8)); v = fmaxf(v,__shfl_xor(v,16)); v = fmaxf(v,__shfl_xor(v,32)); return v;
}
__device__ __forceinline__ double rsumd64(double v){
  v += __shfl_xor(v,1); v += __shfl_xor(v,2); v += __shfl_xor(v,4);
  v += __shfl_xor(v,8); v += __shfl_xor(v,16); v += __shfl_xor(v,32); return v;
}
__device__ __forceinline__ u64 rmaxk64(u64 k){
  u64 o;
  o=__shfl_xor(k,1);  k=k>o?k:o; o=__shfl_xor(k,2);  k=k>o?k:o;
  o=__shfl_xor(k,4);  k=k>o?k:o; o=__shfl_xor(k,8);  k=k>o?k:o;
  o=__shfl_xor(k,16); k=k>o?k:o; o=__shfl_xor(k,32); k=k>o?k:o;
  return k;
}

// ---------------- K0: init workspace head + encout ----------------
__global__ __launch_bounds__(256) void k_init(u32* head, int nhead, float* encout, int nenc) {
  int i = blockIdx.x*blockDim.x + threadIdx.x;
  int st = gridDim.x*blockDim.x;
  for (int k = i; k < nhead; k += st) head[k] = 0u;
  for (int k = i; k < nenc; k += st) encout[k] = 0.f;
}

__global__ __launch_bounds__(64) void k_sentinel(float* out, float v) {
  if (threadIdx.x == 0) out[0] = v;
}

// ---------------- K1: encoder gi GEMM (all steps parallel) ----------------
__global__ __launch_bounds__(512) void k_gi(const int* __restrict__ in_tok, const int* __restrict__ p_ilen,
                                            const float* __restrict__ emb, const float* __restrict__ Wih,
                                            const float* __restrict__ bih, float* __restrict__ gi_buf) {
  int t = blockIdx.x;
  if (t >= p_ilen[0]) return;
  __shared__ float se[H];
  int tid = threadIdx.x;
  if (tid < 64) ((float4*)se)[tid] = ((const float4*)(emb + (size_t)in_tok[t]*H))[tid];
  __syncthreads();
  int w = tid >> 6, l = tid & 63;
  float4 hv = ((const float4*)se)[l];
  for (int rr = 0; rr < 96; ++rr) {
    int row = rr*8 + w;
    float4 wv = ((const float4*)(Wih + (size_t)row*H))[l];
    float acc = dot4(wv, hv, 0.f);
    acc = rsum64(acc);
    if (l == 0) gi_buf[(size_t)t*G3 + row] = acc + bih[row];
  }
}

// ---------------- K2: encoder sequential scan, 16 blocks, seq-slot synced (LDS 50.5KB < 64KB) ----------------
__global__ __launch_bounds__(512) void k_enc(const int* __restrict__ p_ilen, const float* __restrict__ Whh,
                                             const float* __restrict__ bhh, const float* __restrict__ gi_buf,
                                             float* henc /*[2][H]*/, float* encout, u32* eseq) {
  extern __shared__ char smraw[];
  float* sW  = (float*)smraw;        // [48][256]
  float* sh  = sW + 48*H;            // 256
  float* sgh = sh + H;               // 48
  float* sbh = sgh + 48;             // 48
  __shared__ int s_abort;
  int e = blockIdx.x, tid = threadIdx.x;
  int j0 = e*16;
  int ilen = p_ilen[0];
  if (tid == 0) s_abort = 0;
  for (int idx = tid; idx < 48*H; idx += 512) {
    int r = idx >> 8, c = idx & 255;
    int grow = (r>>4)*H + j0 + (r&15);
    sW[idx] = Whh[(size_t)grow*H + c];
  }
  if (tid < 48) { int grow = (tid>>4)*H + j0 + (tid&15); sbh[tid] = bhh[grow]; }
  __syncthreads();
  int w = tid>>6, l = tid&63;
  for (int t = 0; t < ilen; ++t) {
    wait_group(eseq, 16, (u32)t, nullptr, &s_abort, tid);
    if (s_abort) break;
    if (tid < 64) ((float4*)sh)[tid] = ((const float4*)(henc + (t&1)*H))[tid];
    __syncthreads();
    for (int rr = 0; rr < 6; ++rr) {
      int r = rr*8 + w;
      float4 wv = ((const float4*)(sW + r*H))[l];
      float4 hv = ((const float4*)sh)[l];
      float acc = dot4(wv, hv, 0.f);
      acc = rsum64(acc);
      if (l == 0) sgh[r] = acc + sbh[r];
    }
    __syncthreads();
    if (tid < 16) {
      int j = tid;
      const float* gi = gi_buf + (size_t)t*G3;
      float gir = gi[j0+j], giz = gi[H+j0+j], gin = gi[2*H+j0+j];
      float rg = sigf(gir + sgh[j]);
      float zg = sigf(giz + sgh[16+j]);
      float ng = tanhf(fmaf(rg, sgh[32+j], gin));
      float hold = sh[j0+j];
      float h2 = fmaf(zg, hold, (1.f-zg)*ng);
      henc[((t+1)&1)*H + j0 + j] = h2;
      encout[(size_t)t*H + j0 + j] = h2;
    }
    __syncthreads();
    if (tid == 0) { __threadfence(); st32_rel(eseq + (e<<4), (u32)(t+1)); }
  }
}

// ---------------- K3: M = comb_W[:,256:] @ encout^T ; copy final enc h -> hdec buf0 ----------------
__global__ __launch_bounds__(512) void k_m(const int* __restrict__ p_ilen, const float* __restrict__ combW,
                                           const float* __restrict__ encout, float* __restrict__ Mm,
                                           const float* __restrict__ henc, float* __restrict__ hdec) {
  int i = blockIdx.x, tid = threadIdx.x;
  if (i == 256) {
    int ilen = p_ilen[0];
    if (tid < H) hdec[tid] = henc[(ilen&1)*H + tid];
    return;
  }
  __shared__ float sw[H];
  if (tid < 64) ((float4*)sw)[tid] = ((const float4*)(combW + (size_t)i*(2*H) + H))[tid];
  __syncthreads();
  int w = tid>>6, l = tid&63;
  float4 wv = ((const float4*)sw)[l];
  for (int lr = 0; lr < 64; ++lr) {
    int row = lr*8 + w; // 0..511
    float4 ev = ((const float4*)(encout + (size_t)row*H))[l];
    float acc = dot4(wv, ev, 0.f);
    acc = rsum64(acc);
    if (l == 0) Mm[(size_t)i*L_ATT + row] = acc;
  }
}

// ---------------- K4: persistent decoder. ALL weights register-resident (pinned); LDS <= 3.5KB ----------------
__global__ __launch_bounds__(512, 2) void k_dec(
    const int* p_tlen, const int* target,
    const float* __restrict__ dec_emb, const float* __restrict__ attn_W,
    const float* __restrict__ attn_b, const float* __restrict__ comb_W,
    const float* __restrict__ comb_b, const float* __restrict__ Wih,
    const float* __restrict__ Whh, const float* __restrict__ bih,
    const float* __restrict__ bhh, const float* __restrict__ outW,
    const float* __restrict__ outb, const float* __restrict__ Mm,
    float* hdec, float* attnlog, float* ovec,
    double* psum, u64* pkey, float* ltgt_p,
    u64* flagT, u32* aseq, u32* bseq, u32* gseq, u32* vseq,
    float* lossout, int Vv)
{
  extern __shared__ char smraw[];
  __shared__ u64 s_flag;
  __shared__ int s_abort;
  int bid = blockIdx.x, tid = threadIdx.x;
  int tlen = p_tlen[0];
  int w = tid >> 6, l = tid & 63;
  if (tid == 0) s_abort = 0;
  __syncthreads();

  if (bid == 0) {
    // ---------------- control: reduce 196 partials, loss, argmax, publish token ----------------
    double* rd = (double*)smraw;          // [8]
    u64*    rk = (u64*)(smraw + 64);      // [8]
    double loss = 0.0;
    if (tlen <= 0) {
      if (tid == 0) { lossout[0] = 0.f; __threadfence(); st64_rel(flagT, (((u64)1)<<32) | STOPBIT); }
      return;
    }
    for (int s = 0; s < tlen; ++s) {
      wait_group(vseq, NVB, (u32)(s+1), nullptr, &s_abort, tid);
      if (s_abort) {
        if (tid == 0) { lossout[0] = -777.f; __threadfence(); st64_rel(flagT, (((u64)(s+1))<<32) | STOPBIT); }
        break;
      }
      double pd = 0.0; u64 pk = 0ull;
      if (tid < NVB) { pd = psum[tid]; pk = pkey[tid]; }
      pd = rsumd64(pd); pk = rmaxk64(pk);
      if (l == 0) { rd[w] = pd; rk[w] = pk; }
      __syncthreads();
      __shared__ int s_stop;
      if (tid == 0) {
        double ssum = 0.0; u64 key = 0ull;
        for (int k = 0; k < 8; ++k) { ssum += rd[k]; if (rk[k] > key) key = rk[k]; }
        int top = (int)(0xFFFFFFFFu - (u32)(key & 0xFFFFFFFFull));
        float lt = ldf_rlx(ltgt_p);
        loss += log(ssum) - (double)lt;      // -logp[tgt] = lse - logit[tgt]
        bool fin = (top == EOS_TOK) || (s == tlen - 1);
        if (fin) {
          lossout[0] = (float)loss;
          __threadfence();
          st64_rel(flagT, (((u64)(s+1))<<32) | STOPBIT);
        } else {
          st64_rel(flagT, (((u64)(s+1))<<32) | (u64)(u32)top);
        }
        s_stop = fin ? 1 : 0;
      }
      __syncthreads();
      if (s_stop) break;
    }
  } else if (bid < BID_B0) {
    // ---------------- A blocks (16): attn logits, 32 rows each; attn_W pinned in registers ----------------
    int a = bid - BID_A0; int r0 = a*32;
    float* scat = (float*)smraw;          // [512] = [emb | h]
    float* sab  = scat + L_ATT;           // [32]
    int r = tid >> 4, li = tid & 15;      // 32 rows, 16 lanes/row, 32 cols/lane
    float4 aw[8];
    {
      const float4* src = (const float4*)(attn_W + (size_t)(r0 + r)*L_ATT) + li*8;
      #pragma unroll
      for (int k = 0; k < 8; ++k) { aw[k] = src[k]; pin4(aw[k]); }
    }
    if (tid < 32) sab[tid] = attn_b[r0 + tid];
    __syncthreads();
    for (int s = 0; s < tlen; ++s) {
      if (tid == 0) s_flag = spin_flag(flagT, (u32)s);
      __syncthreads();
      u64 f = s_flag;
      if (f & STOPBIT) break;
      int tok = (int)((u32)f & 0x7FFFFFFFu);
      // flag(s) transitively implies h(s) published (ctrl<-V(s-1)<-gseq>=s)
      if (tid < 64)       ((float4*)scat)[tid]      = ((const float4*)(dec_emb + (size_t)tok*H))[tid];
      else if (tid < 128) ((float4*)(scat+H))[tid-64] = ((const float4*)(hdec + (s&1)*H))[tid-64];
      __syncthreads();
      const float4* sc = ((const float4*)scat) + li*8;
      float acc = 0.f;
      #pragma unroll
      for (int k = 0; k < 8; ++k) acc = dot4(aw[k], sc[k], acc);
      acc = rsum16(acc);
      if (li == 0) attnlog[r0 + r] = acc + sab[r];
      __syncthreads();
      if (tid == 0) { __threadfence(); st32_rel(aseq + (a<<4), (u32)(s+1)); }
    }
  } else if (bid < BID_G0) {
    // ---------------- B blocks (8): softmax + o = relu(W1@emb + M@attn/S + b); W1,M pinned ----------------
    int b = bid - BID_B0; int r0 = b*32;
    float* se  = (float*)smraw;          // 256
    float* sal = se + H;                 // 512
    float* sred= sal + L_ATT;            // 32
    float* sce = sred + 32;              // 32
    float* scb = sce + 32;               // 32
    int r = tid >> 4, li = tid & 15;     // 32 rows, 16 lanes/row
    float4 w1[4];   // comb_W[:, :256], 16 cols/lane
    float4 mw[8];   // M rows, 32 cols/lane
    {
      const float4* s1 = (const float4*)(comb_W + (size_t)(r0 + r)*(2*H)) + li*4;
      #pragma unroll
      for (int k = 0; k < 4; ++k) { w1[k] = s1[k]; pin4(w1[k]); }
      const float4* s2 = (const float4*)(Mm + (size_t)(r0 + r)*L_ATT) + li*8;
      #pragma unroll
      for (int k = 0; k < 8; ++k) { mw[k] = s2[k]; pin4(mw[k]); }
    }
    if (tid < 32) scb[tid] = comb_b[r0 + tid];
    __syncthreads();
    for (int s = 0; s < tlen; ++s) {
      if (tid == 0) s_flag = spin_flag(flagT, (u32)s);
      __syncthreads();
      u64 f = s_flag;
      if (f & STOPBIT) break;
      int tok = (int)((u32)f & 0x7FFFFFFFu);
      if (tid < 64) ((float4*)se)[tid] = ((const float4*)(dec_emb + (size_t)tok*H))[tid];
      __syncthreads();
      float ce = 0.f;
      {
        const float4* ee = ((const float4*)se) + li*4;
        #pragma unroll
        for (int k = 0; k < 4; ++k) ce = dot4(w1[k], ee[k], ce);
        ce = rsum16(ce);
      }
      if (li == 0) sce[r] = ce;
      wait_group(aseq, NB_A, (u32)(s+1), flagT, &s_abort, tid);
      if (s_abort) break;
      // softmax over 512 logits (one per thread)
      float x = attnlog[tid];
      float wm = rmaxf64(x);
      if (l == 0) sred[w] = wm;
      __syncthreads();
      if (tid == 0) {
        float m0 = sred[0];
        for (int k = 1; k < 8; ++k) m0 = fmaxf(m0, sred[k]);
        sred[16] = m0;
      }
      __syncthreads();
      float mx = sred[16];
      float e = expf(x - mx);
      sal[tid] = e;
      float wsum = rsum64(e);
      if (l == 0) sred[w] = wsum;
      __syncthreads();
      if (tid == 0) {
        float S0 = 0.f;
        for (int k = 0; k < 8; ++k) S0 += sred[k];
        sred[17] = S0;
      }
      __syncthreads();
      float S = sred[17];
      float acc = 0.f;
      {
        const float4* av = ((const float4*)sal) + li*8;
        #pragma unroll
        for (int k = 0; k < 8; ++k) acc = dot4(mw[k], av[k], acc);
        acc = rsum16(acc);
      }
      if (li == 0) {
        float o = (acc / S) + sce[r] + scb[r];
        ovec[r0 + r] = fmaxf(o, 0.f);
      }
      __syncthreads();
      if (tid == 0) { __threadfence(); st32_rel(bseq + (b<<4), (u32)(s+1)); }
    }
  } else if (bid < BID_V0) {
    // ---------------- G blocks (32): GRU cell, 8 h-elems each; Wih/Whh pinned ----------------
    int g = bid - BID_G0; int j0 = g*8;
    float* sh  = (float*)smraw;          // 256
    float* so  = sh + H;                 // 256
    float* sgh = so + H;                 // 24
    float* sgi = sgh + 24;               // 24
    float* sbi = sgi + 24;               // 24
    float* sbh = sbi + 24;               // 24
    int r = tid >> 4, li = tid & 15;     // 32 row-slots (use 24), 16 lanes, 16 cols/lane
    float4 wih[4], whh[4];
    if (r < 24) {
      int grow = (r>>3)*H + j0 + (r&7);
      const float4* s1 = (const float4*)(Wih + (size_t)grow*H) + li*4;
      const float4* s2 = (const float4*)(Whh + (size_t)grow*H) + li*4;
      #pragma unroll
      for (int k = 0; k < 4; ++k) { wih[k] = s1[k]; pin4(wih[k]); whh[k] = s2[k]; pin4(whh[k]); }
    }
    if (tid < 24) { int grow = (tid>>3)*H + j0 + (tid&7); sbi[tid] = bih[grow]; sbh[tid] = bhh[grow]; }
    __syncthreads();
    for (int s = 0; s < tlen; ++s) {
      wait_group(gseq, NB_G, (u32)s, flagT, &s_abort, tid);   // h(s) ready
      if (s_abort) break;
      if (tid < 64) ((float4*)sh)[tid] = ((const float4*)(hdec + (s&1)*H))[tid];
      __syncthreads();
      if (r < 24) {
        const float4* hv = ((const float4*)sh) + li*4;
        float acc = 0.f;
        #pragma unroll
        for (int k = 0; k < 4; ++k) acc = dot4(whh[k], hv[k], acc);
        acc = rsum16(acc);
        if (li == 0) sgh[r] = acc + sbh[r];
      }
      wait_group(bseq, NB_B, (u32)(s+1), flagT, &s_abort, tid);
      if (s_abort) break;
      if (tid < 64) ((float4*)so)[tid] = ((const float4*)ovec)[tid];
      __syncthreads();
      if (r < 24) {
        const float4* ov = ((const float4*)so) + li*4;
        float acc = 0.f;
        #pragma unroll
        for (int k = 0; k < 4; ++k) acc = dot4(wih[k], ov[k], acc);
        acc = rsum16(acc);
        if (li == 0) sgi[r] = acc + sbi[r];
      }
      __syncthreads();
      if (tid < 8) {
        int j = tid;
        float rg = sigf(sgi[j] + sgh[j]);
        float zg = sigf(sgi[8+j] + sgh[8+j]);
        float ng = tanhf(fmaf(rg, sgh[16+j], sgi[16+j]));
        float hold = sh[j0+j];
        float h2 = fmaf(zg, hold, (1.f-zg)*ng);
        hdec[((s+1)&1)*H + j0 + j] = h2;
      }
      __syncthreads();
      if (tid == 0) { __threadfence(); st32_rel(gseq + (g<<4), (u32)(s+1)); }
    }
  } else {
    // ---------------- V blocks (196): out_W PINNED register-resident. 256 rows/block, 2 thr/row ----------------
    int v = bid - BID_V0;
    float* sh2 = (float*)smraw;                 // 256 floats
    double* swd = (double*)(smraw + 1024);      // [8]
    u64*    swk = (u64*)(smraw + 1024 + 64);    // [8]
    int rowhalf = tid >> 1, s2 = tid & 1;
    int row = v*256 + rowhalf;
    bool valid = (row < Vv);
    const float4* wsrc = (const float4*)(outW + (size_t)(valid ? row : 0)*H) + s2*32;
    float4 wreg[32];
    #pragma unroll
    for (int k = 0; k < 32; ++k) { wreg[k] = wsrc[k]; pin4(wreg[k]); }  // 128 VGPRs, pinned
    float ob = valid ? outb[row] : 0.f;
    for (int s = 0; s < tlen; ++s) {
      wait_group(gseq, NB_G, (u32)(s+1), flagT, &s_abort, tid);  // h(s+1) ready
      if (s_abort) break;
      if (tid < 64) ((float4*)sh2)[tid] = ((const float4*)(hdec + ((s+1)&1)*H))[tid];
      __syncthreads();
      const float4* hp = ((const float4*)sh2) + s2*32;
      float acc = 0.f;
      #pragma unroll
      for (int k = 0; k < 32; ++k) acc = dot4(wreg[k], hp[k], acc);
      acc += __shfl_xor(acc, 1);
      float logit = acc + ob;
      double d = 0.0; u64 key = 0ull;
      if (valid && s2 == 0) {
        if (row == target[s]) stf_rlx(ltgt_p, logit);
        d = (double)expf(logit);
        key = ((u64)f2ord(logit) << 32) | (u64)(0xFFFFFFFFu - (u32)row);
      }
      d = rsumd64(d);
      key = rmaxk64(key);
      if (l == 0) { swd[w] = d; swk[w] = key; }
      __syncthreads();
      if (tid == 0) {
        double dd = 0.0; u64 kk = 0ull;
        for (int k = 0; k < 8; ++k) { dd += swd[k]; if (swk[k] > kk) kk = swk[k]; }
        psum[v] = dd; pkey[v] = kk;
        __threadfence();
        st32_rel(vseq + (v<<4), (u32)(s+1));
      }
      // next wait_group's __syncthreads orders reuse of sh2/swd
    }
  }
}

// ---------------- host launcher ----------------
extern "C" void kernel_launch(void* const* d_in, const int* in_sizes, int n_in,
                              void* d_out, int out_size, void* d_ws, size_t ws_size,
                              hipStream_t stream) {
  const int*   in_tok  = (const int*)d_in[0];
  const int*   p_ilen  = (const int*)d_in[1];
  const int*   tgt_tok = (const int*)d_in[2];
  const int*   p_tlen  = (const int*)d_in[3];
  const float* enc_emb = (const float*)d_in[4];
  const float* dec_emb = (const float*)d_in[5];
  const float* eWih    = (const float*)d_in[6];
  const float* eWhh    = (const float*)d_in[7];
  const float* ebih    = (const float*)d_in[8];
  const float* ebhh    = (const float*)d_in[9];
  const float* dWih    = (const float*)d_in[10];
  const float* dWhh    = (const float*)d_in[11];
  const float* dbih    = (const float*)d_in[12];
  const float* dbhh    = (const float*)d_in[13];
  const float* attn_W  = (const float*)d_in[14];
  const float* attn_b  = (const float*)d_in[15];
  const float* comb_W  = (const float*)d_in[16];
  const float* comb_b  = (const float*)d_in[17];
  const float* outW    = (const float*)d_in[18];
  const float* outb    = (const float*)d_in[19];
  float* lossout = (float*)d_out;

  const int Tin = in_sizes[0];
  const int V   = in_sizes[18] / H;

  if ((V + 255) / 256 > NVB) {
    hipLaunchKernelGGL(k_sentinel, dim3(1), dim3(64), 0, stream, lossout, -12346.f);
    return;
  }
  size_t need = 32768 + (size_t)Tin*G3*4 + (size_t)L_ATT*H*4 + (size_t)H*L_ATT*4;
  if (ws_size < need) {
    hipLaunchKernelGGL(k_sentinel, dim3(1), dim3(64), 0, stream, lossout, -12345.f);
    return;
  }

  char* wsb = (char*)d_ws;
  u64*  flagT = (u64*)(wsb + 0);
  float* ltgt = (float*)(wsb + 128);
  float* henc = (float*)(wsb + 256);             // [2][256]
  float* hdec = (float*)(wsb + 2560);            // [2][256]
  float* attnlog = (float*)(wsb + 4608);         // [512]
  float* ovec    = (float*)(wsb + 6656);         // [256]
  u32*  eseq  = (u32*)(wsb + 8192);              // 16 slots x 64B
  u32*  aseq  = (u32*)(wsb + 9216);              // 16 slots
  u32*  bseq  = (u32*)(wsb + 10240);             // 8 slots
  u32*  gseq  = (u32*)(wsb + 10752);             // 32 slots
  u32*  vseq  = (u32*)(wsb + 12800);             // 196 slots (12.25KB)
  double* psum = (double*)(wsb + 25600);         // [196]
  u64*    pkey = (u64*)(wsb + 27200);            // [196]
  float*  gi_buf  = (float*)(wsb + 32768);       // [Tin][768]
  float*  encout  = gi_buf + (size_t)Tin*G3;     // [512][256]
  float*  Mm      = encout + (size_t)L_ATT*H;    // [256][512]

  hipLaunchKernelGGL(k_init, dim3(64), dim3(256), 0, stream,
                     (u32*)wsb, 32768/4, encout, L_ATT*H);
  hipLaunchKernelGGL(k_gi, dim3(Tin), dim3(512), 0, stream,
                     in_tok, p_ilen, enc_emb, eWih, ebih, gi_buf);
  hipLaunchKernelGGL(k_enc, dim3(16), dim3(512), (48*H + H + 48 + 48)*4, stream,
                     p_ilen, eWhh, ebhh, gi_buf, henc, encout, eseq);
  hipLaunchKernelGGL(k_m, dim3(257), dim3(512), 0, stream,
                     p_ilen, comb_W, encout, Mm, henc, hdec);
  // dynamic LDS tiny (max role need ~3.5KB) -> well under the 64KB per-block launch limit
  hipLaunchKernelGGL(k_dec, dim3(NBLK), dim3(512), 4096, stream,
                     p_tlen, tgt_tok, dec_emb, attn_W, attn_b, comb_W, comb_b,
                     dWih, dWhh, dbih, dbhh, outW, outb, Mm,
                     hdec, attnlog, ovec, psum, pkey, ltgt,
                     flagT, aseq, bseq, gseq, vseq, lossout, V);
}